// Round 1
// baseline (510.764 us; speedup 1.0000x reference)
//
#include <hip/hip_runtime.h>
#include <hip/hip_bf16.h>
#include <cstdint>
#include <cstddef>

// Problem constants
// B=2, T=2048, E=1024, H=16, D=64, BH=32
// SCALING = (64*2)^-0.5
#define SCALING_F 0.08838834764831845f

typedef short bf16x8 __attribute__((ext_vector_type(8)));
typedef float f32x4 __attribute__((ext_vector_type(4)));

__device__ __forceinline__ unsigned short f2bf(float f) {
  unsigned int u = __float_as_uint(f);
  u += 0x7fffu + ((u >> 16) & 1u);   // round-to-nearest-even
  return (unsigned short)(u >> 16);
}

__device__ __forceinline__ f32x4 mfma16(bf16x8 a, bf16x8 b, f32x4 c) {
  return __builtin_amdgcn_mfma_f32_16x16x32_bf16(a, b, c, 0, 0, 0);
}

typedef const __attribute__((address_space(1))) void* as1cp;
typedef __attribute__((address_space(3))) void* as3p;
__device__ __forceinline__ void gload16(const void* g, void* s) {
  // 16B per lane, LDS dest = uniform base + lane*16
  __builtin_amdgcn_global_load_lds((as1cp)g, (as3p)s, 16, 0, 0);
}

// ---------------- fp32 -> bf16 cast ----------------
__global__ void cast_kernel(const float* __restrict__ src,
                            unsigned short* __restrict__ dst, int n) {
  int i = (blockIdx.x * blockDim.x + threadIdx.x) * 4;
  if (i + 4 <= n) {
    float4 v = *reinterpret_cast<const float4*>(src + i);
    ushort4 o;
    o.x = f2bf(v.x); o.y = f2bf(v.y); o.z = f2bf(v.z); o.w = f2bf(v.w);
    *reinterpret_cast<ushort4*>(dst + i) = o;
  }
}

// ---------------- fused QKV GEMM: C = X(4096x1024) * W^T + bias ----------------
// grid (32, 24): blockIdx.y>>3 selects {Wq,Wk,Wv}; 128x128 tile, BK=32, 4 waves.
__global__ __launch_bounds__(256) void gemm_qkv(
    const unsigned short* __restrict__ Xb,
    const unsigned short* __restrict__ Wb,  // q,k,v (,o) at 1048576-elem strides
    const float* __restrict__ bq, const float* __restrict__ bk,
    const float* __restrict__ bv,
    unsigned short* __restrict__ Qb, unsigned short* __restrict__ Kb,
    unsigned short* __restrict__ Vt) {
  __shared__ unsigned short As[128 * 32];
  __shared__ unsigned short Bs[128 * 32];
  const int tid = threadIdx.x, lane = tid & 63, wid = tid >> 6;
  const int mat = blockIdx.y >> 3;
  const int m0 = blockIdx.x * 128, n0 = (blockIdx.y & 7) * 128;
  const unsigned short* W = Wb + (size_t)mat * 1048576;
  const float* bias = (mat == 0) ? bq : (mat == 1 ? bk : bv);

  f32x4 z = {0.f, 0.f, 0.f, 0.f};
  f32x4 acc[4][4];
#pragma unroll
  for (int i = 0; i < 4; ++i)
#pragma unroll
    for (int j = 0; j < 4; ++j) acc[i][j] = z;

  const int wm = wid >> 1, wn = wid & 1;
  const int lr = lane & 15, lg = lane >> 4;

  for (int kt = 0; kt < 1024; kt += 32) {
    __syncthreads();
#pragma unroll
    for (int c = 0; c < 2; ++c) {
      int le = (wid * 2 + c) * 512 + lane * 8;  // element offset in tile
      int row = le >> 5, col = le & 31;
      gload16(Xb + (size_t)(m0 + row) * 1024 + kt + col,
              (void*)(As + (wid * 2 + c) * 512));
      gload16(W + (size_t)(n0 + row) * 1024 + kt + col,
              (void*)(Bs + (wid * 2 + c) * 512));
    }
    __syncthreads();
    bf16x8 a[4], b[4];
#pragma unroll
    for (int f = 0; f < 4; ++f) {
      a[f] = *reinterpret_cast<const bf16x8*>(As + (wm * 64 + f * 16 + lr) * 32 + lg * 8);
      b[f] = *reinterpret_cast<const bf16x8*>(Bs + (wn * 64 + f * 16 + lr) * 32 + lg * 8);
    }
#pragma unroll
    for (int i = 0; i < 4; ++i)
#pragma unroll
      for (int j = 0; j < 4; ++j) acc[i][j] = mfma16(a[i], b[j], acc[i][j]);
  }

  const float scale = (mat == 0) ? SCALING_F : 1.0f;
#pragma unroll
  for (int i = 0; i < 4; ++i) {
#pragma unroll
    for (int j = 0; j < 4; ++j) {
#pragma unroll
      for (int r = 0; r < 4; ++r) {
        int gm = m0 + wm * 64 + i * 16 + lg * 4 + r;  // row (b*T+t)
        int gn = n0 + wn * 64 + j * 16 + lr;          // col (h*64+d)
        float val = (acc[i][j][r] + bias[gn]) * scale;
        int b_ = gm >> 11, t_ = gm & 2047;
        int h_ = gn >> 6, d_ = gn & 63;
        if (mat == 2) {
          // V stored transposed: (bh, d, t)
          Vt[(((size_t)(b_ * 16 + h_)) * 64 + d_) * 2048 + t_] = f2bf(val);
        } else {
          unsigned short* P = (mat == 0) ? Qb : Kb;
          P[(((size_t)(b_ * 16 + h_)) * 2048 + t_) * 64 + d_] = f2bf(val);
        }
      }
    }
  }
}

// ---------------- output GEMM: out = AO(4096x1024) * Wo^T + bo (fp32) ----------------
__global__ __launch_bounds__(256) void gemm_out(
    const unsigned short* __restrict__ Ab, const unsigned short* __restrict__ Wo,
    const float* __restrict__ bo, float* __restrict__ C) {
  __shared__ unsigned short As[128 * 32];
  __shared__ unsigned short Bs[128 * 32];
  const int tid = threadIdx.x, lane = tid & 63, wid = tid >> 6;
  const int m0 = blockIdx.x * 128, n0 = blockIdx.y * 128;

  f32x4 z = {0.f, 0.f, 0.f, 0.f};
  f32x4 acc[4][4];
#pragma unroll
  for (int i = 0; i < 4; ++i)
#pragma unroll
    for (int j = 0; j < 4; ++j) acc[i][j] = z;

  const int wm = wid >> 1, wn = wid & 1;
  const int lr = lane & 15, lg = lane >> 4;

  for (int kt = 0; kt < 1024; kt += 32) {
    __syncthreads();
#pragma unroll
    for (int c = 0; c < 2; ++c) {
      int le = (wid * 2 + c) * 512 + lane * 8;
      int row = le >> 5, col = le & 31;
      gload16(Ab + (size_t)(m0 + row) * 1024 + kt + col,
              (void*)(As + (wid * 2 + c) * 512));
      gload16(Wo + (size_t)(n0 + row) * 1024 + kt + col,
              (void*)(Bs + (wid * 2 + c) * 512));
    }
    __syncthreads();
    bf16x8 a[4], b[4];
#pragma unroll
    for (int f = 0; f < 4; ++f) {
      a[f] = *reinterpret_cast<const bf16x8*>(As + (wm * 64 + f * 16 + lr) * 32 + lg * 8);
      b[f] = *reinterpret_cast<const bf16x8*>(Bs + (wn * 64 + f * 16 + lr) * 32 + lg * 8);
    }
#pragma unroll
    for (int i = 0; i < 4; ++i)
#pragma unroll
      for (int j = 0; j < 4; ++j) acc[i][j] = mfma16(a[i], b[j], acc[i][j]);
  }

#pragma unroll
  for (int i = 0; i < 4; ++i)
#pragma unroll
    for (int j = 0; j < 4; ++j)
#pragma unroll
      for (int r = 0; r < 4; ++r) {
        int gm = m0 + wm * 64 + i * 16 + lg * 4 + r;
        int gn = n0 + wn * 64 + j * 16 + lr;
        C[(size_t)gm * 1024 + gn] = acc[i][j][r] + bo[gn];
      }
}

// ---------------- flash attention with additive bias + mask ----------------
// grid (32 qtiles, 32 bh), 256 thr = 4 waves; wave owns 16 q-rows; kv tiles of 64.
__global__ __launch_bounds__(256) void attn_kernel(
    const unsigned short* __restrict__ Qb,  // (bh, t, d) bf16, pre-scaled
    const unsigned short* __restrict__ Kb,  // (bh, t, d) bf16
    const unsigned short* __restrict__ Vt,  // (bh, d, t) bf16
    const float* __restrict__ bias,         // (32, 2048, 2048) fp32
    const float* __restrict__ mask,         // (2, 1, 2048, 2048) fp32
    const float* __restrict__ c_attn,       // (16) fp32
    unsigned short* __restrict__ AO) {      // (4096, 1024) bf16
  __shared__ unsigned short Plds[4][1024];  // per-wave 16x64 bf16, XOR-swizzled
  const int tid = threadIdx.x, lane = tid & 63, wid = tid >> 6;
  const int bh = blockIdx.y;
  const int b_ = bh >> 4, h_ = bh & 15;
  const int q0 = blockIdx.x * 64 + wid * 16;
  const int lr = lane & 15, lg = lane >> 4;

  const unsigned short* Qp = Qb + ((size_t)bh * 2048 + q0) * 64;
  bf16x8 aq0 = *reinterpret_cast<const bf16x8*>(Qp + lr * 64 + lg * 8);
  bf16x8 aq1 = *reinterpret_cast<const bf16x8*>(Qp + lr * 64 + 32 + lg * 8);

  f32x4 z = {0.f, 0.f, 0.f, 0.f};
  f32x4 o[4] = {z, z, z, z};
  float m_r[4], l_r[4];
#pragma unroll
  for (int r = 0; r < 4; ++r) { m_r[r] = -3.0e38f; l_r[r] = 0.f; }

  const float* brow = bias + (size_t)bh * 2048 * 2048;
  const float* mrow = mask + (size_t)b_ * 2048 * 2048;
  char* pbase = (char*)(&Plds[wid][0]);

  for (int kv0 = 0; kv0 < 2048; kv0 += 64) {
    // ---- S = Q K^T for this wave's 16 q-rows x 64 kv-cols ----
    f32x4 sacc[4] = {z, z, z, z};
    const unsigned short* Kp = Kb + ((size_t)bh * 2048 + kv0) * 64;
#pragma unroll
    for (int f = 0; f < 4; ++f) {
      const unsigned short* kp = Kp + (f * 16 + lr) * 64 + lg * 8;
      bf16x8 k0 = *reinterpret_cast<const bf16x8*>(kp);
      bf16x8 k1 = *reinterpret_cast<const bf16x8*>(kp + 32);
      sacc[f] = mfma16(aq0, k0, sacc[f]);
      sacc[f] = mfma16(aq1, k1, sacc[f]);
    }
    // ---- + bias + mask, tile row-max ----
    float sv[4][4];
    float tmax[4] = {-3.0e38f, -3.0e38f, -3.0e38f, -3.0e38f};
#pragma unroll
    for (int f = 0; f < 4; ++f) {
      int s_ = kv0 + f * 16 + lr;
#pragma unroll
      for (int r = 0; r < 4; ++r) {
        int q_ = q0 + lg * 4 + r;
        float v = sacc[f][r] + brow[(size_t)q_ * 2048 + s_] + mrow[(size_t)q_ * 2048 + s_];
        sv[f][r] = v;
        tmax[r] = fmaxf(tmax[r], v);
      }
    }
#pragma unroll
    for (int r = 0; r < 4; ++r) {
      float t = tmax[r];
      t = fmaxf(t, __shfl_xor(t, 1));
      t = fmaxf(t, __shfl_xor(t, 2));
      t = fmaxf(t, __shfl_xor(t, 4));
      t = fmaxf(t, __shfl_xor(t, 8));
      tmax[r] = fmaxf(m_r[r], t);  // new running max
    }
    float alpha[4], rs[4];
#pragma unroll
    for (int r = 0; r < 4; ++r) {
      alpha[r] = __expf(m_r[r] - tmax[r]);
      m_r[r] = tmax[r];
      rs[r] = 0.f;
    }
    // ---- P = exp(S - m), stage to swizzled LDS ----
#pragma unroll
    for (int f = 0; f < 4; ++f) {
#pragma unroll
      for (int r = 0; r < 4; ++r) {
        float p = __expf(sv[f][r] - m_r[r]);
        rs[r] += p;
        int row = lg * 4 + r;
        int byte = row * 128 + (f * 16 + lr) * 2;
        byte ^= ((row & 7) << 4);
        *reinterpret_cast<unsigned short*>(pbase + byte) = f2bf(p);
      }
    }
#pragma unroll
    for (int r = 0; r < 4; ++r) {
      float t = rs[r];
      t += __shfl_xor(t, 1);
      t += __shfl_xor(t, 2);
      t += __shfl_xor(t, 4);
      t += __shfl_xor(t, 8);
      l_r[r] = l_r[r] * alpha[r] + t;
    }
    // ---- rescale O ----
#pragma unroll
    for (int fd = 0; fd < 4; ++fd)
#pragma unroll
      for (int r = 0; r < 4; ++r) o[fd][r] *= alpha[r];

    asm volatile("s_waitcnt lgkmcnt(0)" ::: "memory");
    // ---- read P as A-fragments (swizzled) ----
    int byte0 = (lr * 128 + lg * 16) ^ ((lr & 7) << 4);
    int byte1 = (lr * 128 + 64 + lg * 16) ^ ((lr & 7) << 4);
    bf16x8 pa0 = *reinterpret_cast<const bf16x8*>(pbase + byte0);
    bf16x8 pa1 = *reinterpret_cast<const bf16x8*>(pbase + byte1);
    // ---- O += P V ----
    const unsigned short* Vp = Vt + (size_t)bh * 64 * 2048 + kv0;
#pragma unroll
    for (int fd = 0; fd < 4; ++fd) {
      const unsigned short* vp = Vp + (size_t)(fd * 16 + lr) * 2048 + lg * 8;
      bf16x8 v0 = *reinterpret_cast<const bf16x8*>(vp);
      bf16x8 v1 = *reinterpret_cast<const bf16x8*>(vp + 32);
      o[fd] = mfma16(pa0, v0, o[fd]);
      o[fd] = mfma16(pa1, v1, o[fd]);
    }
  }

  // ---- normalize, per-head scale, write (b,t,h,d) bf16 ----
  const float ca = c_attn[h_];
#pragma unroll
  for (int fd = 0; fd < 4; ++fd) {
#pragma unroll
    for (int r = 0; r < 4; ++r) {
      int q_ = q0 + lg * 4 + r;
      int d_ = fd * 16 + lr;
      float val = o[fd][r] / l_r[r] * ca;
      AO[((size_t)(b_ * 2048 + q_)) * 1024 + h_ * 64 + d_] = f2bf(val);
    }
  }
}

extern "C" void kernel_launch(void* const* d_in, const int* in_sizes, int n_in,
                              void* d_out, int out_size, void* d_ws, size_t ws_size,
                              hipStream_t stream) {
  const float* hs   = (const float*)d_in[0];
  const float* bias = (const float*)d_in[1];
  const float* mask = (const float*)d_in[2];
  const float* Wq   = (const float*)d_in[3];
  const float* bq   = (const float*)d_in[4];
  const float* Wk   = (const float*)d_in[5];
  const float* bk   = (const float*)d_in[6];
  const float* Wv   = (const float*)d_in[7];
  const float* bv   = (const float*)d_in[8];
  const float* Wo   = (const float*)d_in[9];
  const float* bo   = (const float*)d_in[10];
  const float* ca   = (const float*)d_in[11];
  float* out = (float*)d_out;

  unsigned short* ws = (unsigned short*)d_ws;
  unsigned short* Xb  = ws;                 // 4,194,304
  unsigned short* Wqb = ws + 4194304;       // 3x + Wo: 4,194,304
  unsigned short* Wob = Wqb + 3 * 1048576;
  unsigned short* Qb  = ws + 8388608;       // 4,194,304
  unsigned short* Kb  = Qb + 4194304;
  unsigned short* Vt  = Kb + 4194304;
  unsigned short* AO  = Vt + 4194304;       // total 50,331,648 B

  cast_kernel<<<4096, 256, 0, stream>>>(hs, Xb, 4194304);
  cast_kernel<<<1024, 256, 0, stream>>>(Wq, Wqb, 1048576);
  cast_kernel<<<1024, 256, 0, stream>>>(Wk, Wqb + 1048576, 1048576);
  cast_kernel<<<1024, 256, 0, stream>>>(Wv, Wqb + 2 * 1048576, 1048576);
  cast_kernel<<<1024, 256, 0, stream>>>(Wo, Wob, 1048576);

  gemm_qkv<<<dim3(32, 24), 256, 0, stream>>>(Xb, Wqb, bq, bk, bv, Qb, Kb, Vt);
  attn_kernel<<<dim3(32, 32), 256, 0, stream>>>(Qb, Kb, Vt, bias, mask, ca, AO);
  gemm_out<<<dim3(32, 8), 256, 0, stream>>>(AO, Wob, bo, out);
}

// Round 2
// 442.733 us; speedup vs baseline: 1.1537x; 1.1537x over previous
//
#include <hip/hip_runtime.h>
#include <hip/hip_bf16.h>
#include <cstdint>
#include <cstddef>

// Problem constants: B=2, T=2048, E=1024, H=16, D=64, BH=32
#define SCALING_F 0.08838834764831845f

typedef short bf16x8 __attribute__((ext_vector_type(8)));
typedef float f32x4 __attribute__((ext_vector_type(4)));

__device__ __forceinline__ unsigned short f2bf(float f) {
  unsigned int u = __float_as_uint(f);
  u += 0x7fffu + ((u >> 16) & 1u);   // round-to-nearest-even
  return (unsigned short)(u >> 16);
}

__device__ __forceinline__ f32x4 mfma16(bf16x8 a, bf16x8 b, f32x4 c) {
  return __builtin_amdgcn_mfma_f32_16x16x32_bf16(a, b, c, 0, 0, 0);
}

typedef const __attribute__((address_space(1))) void* as1cp;
typedef __attribute__((address_space(3))) void* as3p;
__device__ __forceinline__ void gload16(const void* g, void* s) {
  __builtin_amdgcn_global_load_lds((as1cp)g, (as3p)s, 16, 0, 0);
}

// ---------------- fp32 -> bf16 cast ----------------
__global__ void cast_kernel(const float* __restrict__ src,
                            unsigned short* __restrict__ dst, int n) {
  int i = (blockIdx.x * blockDim.x + threadIdx.x) * 4;
  if (i + 4 <= n) {
    float4 v = *reinterpret_cast<const float4*>(src + i);
    ushort4 o;
    o.x = f2bf(v.x); o.y = f2bf(v.y); o.z = f2bf(v.z); o.w = f2bf(v.w);
    *reinterpret_cast<ushort4*>(dst + i) = o;
  }
}

// ---------------- fused QKV GEMM: C = X(4096x1024) * W^T + bias ----------------
__global__ __launch_bounds__(256) void gemm_qkv(
    const unsigned short* __restrict__ Xb,
    const unsigned short* __restrict__ Wb,
    const float* __restrict__ bq, const float* __restrict__ bk,
    const float* __restrict__ bv,
    unsigned short* __restrict__ Qb, unsigned short* __restrict__ Kb,
    unsigned short* __restrict__ Vt) {
  __shared__ unsigned short As[128 * 32];
  __shared__ unsigned short Bs[128 * 32];
  const int tid = threadIdx.x, lane = tid & 63, wid = tid >> 6;
  const int mat = blockIdx.y >> 3;
  const int m0 = blockIdx.x * 128, n0 = (blockIdx.y & 7) * 128;
  const unsigned short* W = Wb + (size_t)mat * 1048576;
  const float* bias = (mat == 0) ? bq : (mat == 1 ? bk : bv);

  f32x4 z = {0.f, 0.f, 0.f, 0.f};
  f32x4 acc[4][4];
#pragma unroll
  for (int i = 0; i < 4; ++i)
#pragma unroll
    for (int j = 0; j < 4; ++j) acc[i][j] = z;

  const int wm = wid >> 1, wn = wid & 1;
  const int lr = lane & 15, lg = lane >> 4;

  for (int kt = 0; kt < 1024; kt += 32) {
    __syncthreads();
#pragma unroll
    for (int c = 0; c < 2; ++c) {
      int le = (wid * 2 + c) * 512 + lane * 8;
      int row = le >> 5, col = le & 31;
      gload16(Xb + (size_t)(m0 + row) * 1024 + kt + col,
              (void*)(As + (wid * 2 + c) * 512));
      gload16(W + (size_t)(n0 + row) * 1024 + kt + col,
              (void*)(Bs + (wid * 2 + c) * 512));
    }
    __syncthreads();
    bf16x8 a[4], b[4];
#pragma unroll
    for (int f = 0; f < 4; ++f) {
      a[f] = *reinterpret_cast<const bf16x8*>(As + (wm * 64 + f * 16 + lr) * 32 + lg * 8);
      b[f] = *reinterpret_cast<const bf16x8*>(Bs + (wn * 64 + f * 16 + lr) * 32 + lg * 8);
    }
#pragma unroll
    for (int i = 0; i < 4; ++i)
#pragma unroll
      for (int j = 0; j < 4; ++j) acc[i][j] = mfma16(a[i], b[j], acc[i][j]);
  }

  const float scale = (mat == 0) ? SCALING_F : 1.0f;
#pragma unroll
  for (int i = 0; i < 4; ++i) {
#pragma unroll
    for (int j = 0; j < 4; ++j) {
#pragma unroll
      for (int r = 0; r < 4; ++r) {
        int gm = m0 + wm * 64 + i * 16 + lg * 4 + r;
        int gn = n0 + wn * 64 + j * 16 + lr;
        float val = (acc[i][j][r] + bias[gn]) * scale;
        int b_ = gm >> 11, t_ = gm & 2047;
        int h_ = gn >> 6, d_ = gn & 63;
        if (mat == 2) {
          Vt[(((size_t)(b_ * 16 + h_)) * 64 + d_) * 2048 + t_] = f2bf(val);
        } else {
          unsigned short* P = (mat == 0) ? Qb : Kb;
          P[(((size_t)(b_ * 16 + h_)) * 2048 + t_) * 64 + d_] = f2bf(val);
        }
      }
    }
  }
}

// ---------------- output GEMM: out = AO(4096x1024) * Wo^T + bo (fp32) ----------------
__global__ __launch_bounds__(256) void gemm_out(
    const unsigned short* __restrict__ Ab, const unsigned short* __restrict__ Wo,
    const float* __restrict__ bo, float* __restrict__ C) {
  __shared__ unsigned short As[128 * 32];
  __shared__ unsigned short Bs[128 * 32];
  const int tid = threadIdx.x, lane = tid & 63, wid = tid >> 6;
  const int m0 = blockIdx.x * 128, n0 = blockIdx.y * 128;

  f32x4 z = {0.f, 0.f, 0.f, 0.f};
  f32x4 acc[4][4];
#pragma unroll
  for (int i = 0; i < 4; ++i)
#pragma unroll
    for (int j = 0; j < 4; ++j) acc[i][j] = z;

  const int wm = wid >> 1, wn = wid & 1;
  const int lr = lane & 15, lg = lane >> 4;

  for (int kt = 0; kt < 1024; kt += 32) {
    __syncthreads();
#pragma unroll
    for (int c = 0; c < 2; ++c) {
      int le = (wid * 2 + c) * 512 + lane * 8;
      int row = le >> 5, col = le & 31;
      gload16(Ab + (size_t)(m0 + row) * 1024 + kt + col,
              (void*)(As + (wid * 2 + c) * 512));
      gload16(Wo + (size_t)(n0 + row) * 1024 + kt + col,
              (void*)(Bs + (wid * 2 + c) * 512));
    }
    __syncthreads();
    bf16x8 a[4], b[4];
#pragma unroll
    for (int f = 0; f < 4; ++f) {
      a[f] = *reinterpret_cast<const bf16x8*>(As + (wm * 64 + f * 16 + lr) * 32 + lg * 8);
      b[f] = *reinterpret_cast<const bf16x8*>(Bs + (wn * 64 + f * 16 + lr) * 32 + lg * 8);
    }
#pragma unroll
    for (int i = 0; i < 4; ++i)
#pragma unroll
      for (int j = 0; j < 4; ++j) acc[i][j] = mfma16(a[i], b[j], acc[i][j]);
  }

#pragma unroll
  for (int i = 0; i < 4; ++i)
#pragma unroll
    for (int j = 0; j < 4; ++j)
#pragma unroll
      for (int r = 0; r < 4; ++r) {
        int gm = m0 + wm * 64 + i * 16 + lg * 4 + r;
        int gn = n0 + wn * 64 + j * 16 + lr;
        C[(size_t)gm * 1024 + gn] = acc[i][j][r] + bo[gn];
      }
}

// ---------------- flash attention, S^T layout + vectorized bias ----------------
// grid (32 qtiles, 32 bh), 4 waves; wave owns 16 q-rows; kv tiles of 64.
// S^T via mfma(K,Q): lane holds q = q0+lr (col), s = kv0+f*16+lg*4+r (row).
__global__ __launch_bounds__(256) void attn_kernel(
    const unsigned short* __restrict__ Qb,  // (bh, t, d) bf16, pre-scaled
    const unsigned short* __restrict__ Kb,  // (bh, t, d) bf16
    const unsigned short* __restrict__ Vt,  // (bh, d, t) bf16
    const float* __restrict__ bias,         // (32, 2048, 2048) fp32
    const float* __restrict__ mask,         // (2, 1, 2048, 2048) fp32
    const float* __restrict__ c_attn,       // (16) fp32
    unsigned short* __restrict__ AO) {      // (4096, 1024) bf16
  __shared__ unsigned short Plds[4][1024];  // per-wave 16x64 bf16, XOR-swizzled
  const int tid = threadIdx.x, lane = tid & 63, wid = tid >> 6;
  const int bh = blockIdx.y;
  const int b_ = bh >> 4, h_ = bh & 15;
  const int q0 = blockIdx.x * 64 + wid * 16;
  const int lr = lane & 15, lg = lane >> 4;

  const unsigned short* Qp = Qb + ((size_t)bh * 2048 + q0) * 64;
  // Q as B-fragment: col q=lr, k=d
  bf16x8 bq0 = *reinterpret_cast<const bf16x8*>(Qp + lr * 64 + lg * 8);
  bf16x8 bq1 = *reinterpret_cast<const bf16x8*>(Qp + lr * 64 + 32 + lg * 8);

  f32x4 z = {0.f, 0.f, 0.f, 0.f};
  f32x4 o[4] = {z, z, z, z};
  float m_q = -3.0e38f, l_q = 0.f;  // per-lane running stats for q = q0+lr

  // per-lane row base: bias[q0+lr][lg*4 + ...]
  const float* bptr = bias + (size_t)bh * 2048 * 2048 + (size_t)(q0 + lr) * 2048 + lg * 4;
  const float* mptr = mask + (size_t)b_ * 2048 * 2048 + (size_t)(q0 + lr) * 2048 + lg * 4;
  char* pbase = (char*)(&Plds[wid][0]);

  auto process = [&](int kv0, const float4* bb) {
    // mask (L3-resident, loaded in-tile)
    float4 mmv[4];
#pragma unroll
    for (int f = 0; f < 4; ++f)
      mmv[f] = *reinterpret_cast<const float4*>(mptr + kv0 + f * 16);

    // S^T = (K tile) x (Q tile)
    f32x4 sacc[4] = {z, z, z, z};
    const unsigned short* Kp = Kb + ((size_t)bh * 2048 + kv0) * 64;
#pragma unroll
    for (int f = 0; f < 4; ++f) {
      const unsigned short* kp = Kp + (f * 16 + lr) * 64 + lg * 8;
      bf16x8 k0 = *reinterpret_cast<const bf16x8*>(kp);
      bf16x8 k1 = *reinterpret_cast<const bf16x8*>(kp + 32);
      sacc[f] = mfma16(k0, bq0, sacc[f]);
      sacc[f] = mfma16(k1, bq1, sacc[f]);
    }

    // add bias + mask, within-lane max over 16 s-values
    float tmax = -3.0e38f;
#pragma unroll
    for (int f = 0; f < 4; ++f) {
#pragma unroll
      for (int r = 0; r < 4; ++r) {
        float bv = (f == 0) ? bb[0][r] : (f == 1) ? bb[1][r] : (f == 2) ? bb[2][r] : bb[3][r];
        float mv = (f == 0) ? mmv[0][r] : (f == 1) ? mmv[1][r] : (f == 2) ? mmv[2][r] : mmv[3][r];
        float v = sacc[f][r] + bv + mv;
        sacc[f][r] = v;
        tmax = fmaxf(tmax, v);
      }
    }
    tmax = fmaxf(tmax, __shfl_xor(tmax, 16));
    tmax = fmaxf(tmax, __shfl_xor(tmax, 32));
    float mnew = fmaxf(m_q, tmax);
    float alpha = __expf(m_q - mnew);
    m_q = mnew;

    // P = exp(S - m), pack to bf16 pairs, row sum
    float rs = 0.f;
    unsigned int pk0[4], pk1[4];
#pragma unroll
    for (int f = 0; f < 4; ++f) {
      float p0 = __expf(sacc[f][0] - mnew);
      float p1 = __expf(sacc[f][1] - mnew);
      float p2 = __expf(sacc[f][2] - mnew);
      float p3 = __expf(sacc[f][3] - mnew);
      rs += (p0 + p1) + (p2 + p3);
      pk0[f] = (unsigned)f2bf(p0) | ((unsigned)f2bf(p1) << 16);
      pk1[f] = (unsigned)f2bf(p2) | ((unsigned)f2bf(p3) << 16);
    }
    rs += __shfl_xor(rs, 16);
    rs += __shfl_xor(rs, 32);
    l_q = l_q * alpha + rs;

    // write P[q=lr][s=f*16+lg*4 .. +3] as 8B, XOR-swizzled by q-row
#pragma unroll
    for (int f = 0; f < 4; ++f) {
      int byte = (lr * 128 + (f * 16 + lg * 4) * 2) ^ ((lr & 7) << 4);
      uint2 w; w.x = pk0[f]; w.y = pk1[f];
      *reinterpret_cast<uint2*>(pbase + byte) = w;
    }

    // rescale O: alpha lives on lane lr==q; o rows are q=lg*4+r
    float al0 = __shfl(alpha, lg * 4 + 0);
    float al1 = __shfl(alpha, lg * 4 + 1);
    float al2 = __shfl(alpha, lg * 4 + 2);
    float al3 = __shfl(alpha, lg * 4 + 3);
#pragma unroll
    for (int fd = 0; fd < 4; ++fd) {
      o[fd][0] *= al0; o[fd][1] *= al1; o[fd][2] *= al2; o[fd][3] *= al3;
    }

    asm volatile("s_waitcnt lgkmcnt(0)" ::: "memory");
    __builtin_amdgcn_sched_barrier(0);

    // read P as A-fragments (swizzled): row q=lr, k=s
    int byte0 = (lr * 128 + lg * 16) ^ ((lr & 7) << 4);
    int byte1 = (lr * 128 + 64 + lg * 16) ^ ((lr & 7) << 4);
    bf16x8 pa0 = *reinterpret_cast<const bf16x8*>(pbase + byte0);
    bf16x8 pa1 = *reinterpret_cast<const bf16x8*>(pbase + byte1);

    // O += P V
    const unsigned short* Vp = Vt + (size_t)bh * 131072 + kv0;
#pragma unroll
    for (int fd = 0; fd < 4; ++fd) {
      const unsigned short* vp = Vp + (size_t)(fd * 16 + lr) * 2048 + lg * 8;
      bf16x8 v0 = *reinterpret_cast<const bf16x8*>(vp);
      bf16x8 v1 = *reinterpret_cast<const bf16x8*>(vp + 32);
      o[fd] = mfma16(pa0, v0, o[fd]);
      o[fd] = mfma16(pa1, v1, o[fd]);
    }
  };

  // software pipeline: bias prefetched one kv-tile ahead (double-buffered regs)
  float4 bbA[4], bbB[4];
#pragma unroll
  for (int f = 0; f < 4; ++f)
    bbA[f] = *reinterpret_cast<const float4*>(bptr + f * 16);

  for (int kv0 = 0; kv0 < 2048; kv0 += 128) {
#pragma unroll
    for (int f = 0; f < 4; ++f)
      bbB[f] = *reinterpret_cast<const float4*>(bptr + kv0 + 64 + f * 16);
    process(kv0, bbA);
    if (kv0 + 128 < 2048) {
#pragma unroll
      for (int f = 0; f < 4; ++f)
        bbA[f] = *reinterpret_cast<const float4*>(bptr + kv0 + 128 + f * 16);
    }
    process(kv0 + 64, bbB);
  }

  // normalize, per-head scale, write (b,t,h,d) bf16
  float linv = 1.0f / l_q;
  float li0 = __shfl(linv, lg * 4 + 0);
  float li1 = __shfl(linv, lg * 4 + 1);
  float li2 = __shfl(linv, lg * 4 + 2);
  float li3 = __shfl(linv, lg * 4 + 3);
  const float ca = c_attn[h_];
#pragma unroll
  for (int fd = 0; fd < 4; ++fd) {
    float li[4] = {li0, li1, li2, li3};
#pragma unroll
    for (int r = 0; r < 4; ++r) {
      int q_ = q0 + lg * 4 + r;
      int d_ = fd * 16 + lr;
      AO[((size_t)(b_ * 2048 + q_)) * 1024 + h_ * 64 + d_] = f2bf(o[fd][r] * li[r] * ca);
    }
  }
}

extern "C" void kernel_launch(void* const* d_in, const int* in_sizes, int n_in,
                              void* d_out, int out_size, void* d_ws, size_t ws_size,
                              hipStream_t stream) {
  const float* hs   = (const float*)d_in[0];
  const float* bias = (const float*)d_in[1];
  const float* mask = (const float*)d_in[2];
  const float* Wq   = (const float*)d_in[3];
  const float* bq   = (const float*)d_in[4];
  const float* Wk   = (const float*)d_in[5];
  const float* bk   = (const float*)d_in[6];
  const float* Wv   = (const float*)d_in[7];
  const float* bv   = (const float*)d_in[8];
  const float* Wo   = (const float*)d_in[9];
  const float* bo   = (const float*)d_in[10];
  const float* ca   = (const float*)d_in[11];
  float* out = (float*)d_out;

  unsigned short* ws = (unsigned short*)d_ws;
  unsigned short* Xb  = ws;
  unsigned short* Wqb = ws + 4194304;
  unsigned short* Wob = Wqb + 3 * 1048576;
  unsigned short* Qb  = ws + 8388608;
  unsigned short* Kb  = Qb + 4194304;
  unsigned short* Vt  = Kb + 4194304;
  unsigned short* AO  = Vt + 4194304;

  cast_kernel<<<4096, 256, 0, stream>>>(hs, Xb, 4194304);
  cast_kernel<<<1024, 256, 0, stream>>>(Wq, Wqb, 1048576);
  cast_kernel<<<1024, 256, 0, stream>>>(Wk, Wqb + 1048576, 1048576);
  cast_kernel<<<1024, 256, 0, stream>>>(Wv, Wqb + 2 * 1048576, 1048576);
  cast_kernel<<<1024, 256, 0, stream>>>(Wo, Wob, 1048576);

  gemm_qkv<<<dim3(32, 24), 256, 0, stream>>>(Xb, Wqb, bq, bk, bv, Qb, Kb, Vt);
  attn_kernel<<<dim3(32, 32), 256, 0, stream>>>(Qb, Kb, Vt, bias, mask, ca, AO);
  gemm_out<<<dim3(32, 8), 256, 0, stream>>>(AO, Wob, bo, out);
}